// Round 14
// baseline (863.184 us; speedup 1.0000x reference)
//
#include <hip/hip_runtime.h>
#include <hip/hip_bf16.h>

#define B_ 16
#define T_ 12
#define N_ 2048
#define C_ 64
#define NW_ 10
#define K_ 6144  // WIN*N

#define NT32 192       // k32 phases
#define BLDS32 10240   // B elems per k32 LDS buffer (320 cols x 32 k)

typedef __attribute__((ext_vector_type(8))) short bf16x8;
typedef __attribute__((ext_vector_type(4))) float f32x4;

__device__ __forceinline__ unsigned short f2bf(float f) {
  union { float f; unsigned int u; } v; v.f = f;
  unsigned int u = v.u;
  return (unsigned short)((u + 0x7FFFu + ((u >> 16) & 1u)) >> 16);  // RNE
}

__device__ __forceinline__ void gload16(const void* g, void* l) {
  __builtin_amdgcn_global_load_lds(
      (const __attribute__((address_space(1))) unsigned int*)g,
      (__attribute__((address_space(3))) unsigned int*)l, 16, 0, 0);
}

template<int N>
__device__ __forceinline__ void vmw() {
  if constexpr (N == 30)      asm volatile("s_waitcnt vmcnt(30)" ::: "memory");
  else if constexpr (N == 25) asm volatile("s_waitcnt vmcnt(25)" ::: "memory");
  else if constexpr (N == 22) asm volatile("s_waitcnt vmcnt(22)" ::: "memory");
  else if constexpr (N == 16) asm volatile("s_waitcnt vmcnt(16)" ::: "memory");
  else                        asm volatile("s_waitcnt vmcnt(0)" ::: "memory");
}

// ---- prep: x = data + temb + semb -> bf16, blocked layout ----
// xbt2[(b*T+t)*32 + nb][o(8)][c(64)][e(8)] = x[b][t][n=nb*64+o*8+e][c]
__global__ __launch_bounds__(256) void prep_x2(const float* __restrict__ data,
                                               const float* __restrict__ temb,
                                               const float* __restrict__ semb,
                                               unsigned short* __restrict__ xbt2) {
  int idx = blockIdx.x * 256 + threadIdx.x;   // [0, 3145728)
  int q = idx & 511;
  int btnb = idx >> 9;
  int nb = btnb & 31;
  int bt = btnb >> 5;            // b*T + t, < 192
  int t = bt % T_;
  int o = q >> 6, c = q & 63;
  int n0 = nb * 64 + o * 8;
  float te = temb[t * C_ + c];
  union { unsigned short s[8]; uint4 v; } pk;
#pragma unroll
  for (int e = 0; e < 8; ++e) {
    int n = n0 + e;
    float d = data[((size_t)bt * N_ + n) * C_ + c];
    float se = semb[(size_t)n * C_ + c];
    pk.s[e] = f2bf(d + te + se);
  }
  *(uint4*)(xbt2 + (size_t)idx * 8) = pk.v;
}

// ---- prep: adj_mid rows [N..2N) -> bm128-tile granule layout ----
// granule g: s=g&63 (l4=s>>4,l15=s&15); chunk=g>>6: rg=chunk&7, KK=(chunk>>3)&1,
// t=(chunk>>4)%96, bmt=(chunk>>4)/96; elem j = adj_mid[bmt*128+rg*16+l15][t*64+KK*32+l4*8+j]
__global__ __launch_bounds__(256) void prep_adj3(const float* __restrict__ adj,
                                                 unsigned short* __restrict__ adjb3) {
  int idx = blockIdx.x * 256 + threadIdx.x;   // 1,572,864 granules
  int s = idx & 63;
  int l4 = s >> 4, l15 = s & 15;
  int chunk = idx >> 6;
  int rg = chunk & 7;
  int KK = (chunk >> 3) & 1;
  int tb = chunk >> 4;
  int t = tb % 96;
  int bmt = tb / 96;
  int m = bmt * 128 + rg * 16 + l15;
  int k = t * 64 + KK * 32 + l4 * 8;
  const float* src = adj + ((size_t)(N_ + m)) * K_ + k;
  float4 a = *(const float4*)src;
  float4 b4 = *(const float4*)(src + 4);
  union { unsigned short s8[8]; uint4 v; } pk;
  pk.s8[0] = f2bf(a.x);  pk.s8[1] = f2bf(a.y);  pk.s8[2] = f2bf(a.z);  pk.s8[3] = f2bf(a.w);
  pk.s8[4] = f2bf(b4.x); pk.s8[5] = f2bf(b4.y); pk.s8[6] = f2bf(b4.z); pk.s8[7] = f2bf(b4.w);
  *(uint4*)(adjb3 + (size_t)idx * 8) = pk.v;
}

// ---- prep: W -> bf16 transposed [w][f][d][c] ----
__global__ __launch_bounds__(256) void prep_w(const float* __restrict__ W,
                                              unsigned short* __restrict__ wbt) {
  int idx = blockIdx.x * 256 + threadIdx.x;
  int c = idx & 63;
  int d = (idx >> 6) & 127;
  int wf = idx >> 13;
  float v = W[((size_t)wf * 64 + c) * 128 + d];
  wbt[idx] = f2bf(v);
}

// ---- main GEMM: 4-wave blocks, 2/CU, ZERO barriers in K-loop.
// A: global->VGPR (af_lo prefetched 1 phase ahead, af_hi in-phase w/ 20-MFMA lead; L1
//    absorbs 4-wave duplication). B: wave-PRIVATE LDS chunks, 3-buf, same-wave vmcnt
//    ledger. 8 independent wave pipelines per CU.
struct SegCtx {
  const unsigned short* Asrc;    // adjb3 + bmt*786432
  const unsigned short* Xroot;   // xbt2 + (b*T + w0)*C*N
  int wid5, fbase;
  int bconst[5];                 // per-chunk B src offset (incl. lane term)
};

// vm ledger (issue order pinned by "memory" fences): per steady phase 13 vm ops
// [ahi 4][Bstage 5][aloN 4]; wait before ds_reads guarantees B(u) (staged u-2) landed:
// u=0 -> 22, 1<=u<=189 -> 30, u=190 -> 25, u=191 -> 16.
template<int U3>
__device__ __forceinline__ void phase32(const SegCtx& s, unsigned short* ldsB, int u,
                                        bf16x8 (&alo)[4], bf16x8 (&aloN)[4],
                                        f32x4 (&acc)[8][5]) {
  const unsigned short* Au = s.Asrc + (size_t)u * 4096;
  bf16x8 ahi[4];
#pragma unroll
  for (int i = 0; i < 4; ++i)
    ahi[i] = *(const bf16x8*)(Au + (4 + i) * 512 + s.fbase);
  if (u + 2 < NT32) {
    const unsigned short* Bs = s.Xroot + (size_t)(u + 2) * 2048;
    unsigned short* Bd = ldsB + ((U3 + 2) % 3) * BLDS32;
#pragma unroll
    for (int ci = 0; ci < 5; ++ci)
      gload16(Bs + s.bconst[ci], Bd + (s.wid5 + ci) * 512);
  }
  if (u + 1 < NT32) {
    const unsigned short* An = Au + 4096;
#pragma unroll
    for (int i = 0; i < 4; ++i)
      aloN[i] = *(const bf16x8*)(An + i * 512 + s.fbase);
  }
  if (u == 0) vmw<22>();
  else if (u < NT32 - 2) vmw<30>();
  else if (u == NT32 - 2) vmw<25>();
  else vmw<16>();
  const unsigned short* Bb = ldsB + U3 * BLDS32;
  bf16x8 bfv[5];
#pragma unroll
  for (int c = 0; c < 5; ++c)
    bfv[c] = *(const bf16x8*)(Bb + (s.wid5 + c) * 512 + s.fbase);
  __builtin_amdgcn_s_setprio(1);
#pragma unroll
  for (int i = 0; i < 4; ++i)
#pragma unroll
    for (int c = 0; c < 5; ++c)
      acc[i][c] = __builtin_amdgcn_mfma_f32_16x16x32_bf16(alo[i], bfv[c], acc[i][c], 0, 0, 0);
#pragma unroll
  for (int i = 0; i < 4; ++i)
#pragma unroll
    for (int c = 0; c < 5; ++c)
      acc[4 + i][c] = __builtin_amdgcn_mfma_f32_16x16x32_bf16(ahi[i], bfv[c], acc[4 + i][c], 0, 0, 0);
  __builtin_amdgcn_s_setprio(0);
  __builtin_amdgcn_sched_barrier(0);
}

__global__ __launch_bounds__(256, 2) void gemm_agg(const unsigned short* __restrict__ adjb3,
                                                   const unsigned short* __restrict__ xbt2,
                                                   unsigned short* __restrict__ aggb) {
  __shared__ __align__(16) unsigned short ldsB[3 * BLDS32];   // 60KB
  int bid = blockIdx.x;
  int bmt = bid & 15;               // bid&7 == bmt&7 -> XCD-resident A (2x1.5MB)
  int bs = bid >> 4;
  int b = bs >> 1;
  int w0 = (bs & 1) * 5;
  int tid = threadIdx.x;
  int lane = tid & 63, wid = tid >> 6;
  int l4 = lane >> 4, l15 = lane & 15;
  SegCtx s;
  s.wid5 = wid * 5;
  s.fbase = l4 * 128 + l15 * 8;
  s.Asrc = adjb3 + (size_t)bmt * 786432;
  s.Xroot = xbt2 + ((size_t)(b * T_ + w0)) * C_ * N_;
  int bOffLane = l4 * 512 + l15 * 8;
#pragma unroll
  for (int ci = 0; ci < 5; ++ci) {
    int cg = s.wid5 + ci;
    s.bconst[ci] = (cg >> 2) * 131072 + (cg & 3) * 128 + bOffLane;
  }

  f32x4 acc[8][5];
#pragma unroll
  for (int i = 0; i < 8; ++i)
#pragma unroll
    for (int c = 0; c < 5; ++c) acc[i][c] = (f32x4)0.f;

  bf16x8 P[4], Q[4];
  // prologue (no barrier): B(0)->buf0 [ops 1-5], B(1)->buf1 [6-10], alo(0)->P [11-14]
  __builtin_amdgcn_sched_barrier(0);
#pragma unroll
  for (int ci = 0; ci < 5; ++ci)
    gload16(s.Xroot + s.bconst[ci], ldsB + (s.wid5 + ci) * 512);
#pragma unroll
  for (int ci = 0; ci < 5; ++ci)
    gload16(s.Xroot + 2048 + s.bconst[ci], ldsB + BLDS32 + (s.wid5 + ci) * 512);
#pragma unroll
  for (int i = 0; i < 4; ++i)
    P[i] = *(const bf16x8*)(s.Asrc + i * 512 + s.fbase);
  __builtin_amdgcn_sched_barrier(0);

  for (int it = 0; it < NT32 / 6; ++it) {
    int u = it * 6;
    phase32<0>(s, ldsB, u,     P, Q, acc);
    phase32<1>(s, ldsB, u + 1, Q, P, acc);
    phase32<2>(s, ldsB, u + 2, P, Q, acc);
    phase32<0>(s, ldsB, u + 3, Q, P, acc);
    phase32<1>(s, ldsB, u + 4, P, Q, acc);
    phase32<2>(s, ldsB, u + 5, Q, P, acc);
  }

  // C-write: bf16 agg [bw][n][c]
  unsigned short* Ob0 = aggb + (size_t)(b * NW_ + w0) * N_ * C_;
#pragma unroll
  for (int c = 0; c < 5; ++c) {
    int col = wid * 80 + c * 16 + l15;
    int g = col >> 6, cc = col & 63;
    unsigned short* Ob = Ob0 + (size_t)g * N_ * C_ + cc;
#pragma unroll
    for (int i = 0; i < 8; ++i) {
      int n0 = bmt * 128 + i * 16 + l4 * 4;
#pragma unroll
      for (int q = 0; q < 4; ++q)
        Ob[(size_t)(n0 + q) * C_] = f2bf(acc[i][c][q]);
    }
  }
}

// ---- epilogue: pre = agg @ W[w,f] + b; glu; max over f ----
__global__ __launch_bounds__(256) void glu_out(const unsigned short* __restrict__ aggb,
                                               const unsigned short* __restrict__ wbt,
                                               const float* __restrict__ bias,
                                               float* __restrict__ out) {
  __shared__ __align__(16) unsigned short sW[3 * 128 * 64];
  int bn = blockIdx.x, bw = blockIdx.y;
  int w = bw % NW_;
  int tid = threadIdx.x, lane = tid & 63, wid = tid >> 6;
  int lrow8 = lane >> 3, jl = lane & 7;
  int l15 = lane & 15, l4 = lane >> 4;
  const unsigned short* Wsrc = wbt + (size_t)w * 3 * 128 * 64;
  for (int ci = 0; ci < 12; ++ci) {
    int chunk = wid * 12 + ci;
    int row = chunk * 8 + lrow8;
    int jg = jl ^ (row & 7);
    gload16(Wsrc + (size_t)row * 64 + jg * 8, &sW[chunk * 512]);
  }
  const unsigned short* Abase = aggb + ((size_t)bw * N_ + bn * 128 + wid * 32) * C_;
  bf16x8 af[2][2];
  for (int i = 0; i < 2; ++i)
    for (int kh = 0; kh < 2; ++kh)
      af[i][kh] = *(const bf16x8*)(Abase + (size_t)(i * 16 + l15) * C_ + kh * 32 + l4 * 8);
  __syncthreads();

  float omax[2][4][4];
  for (int i = 0; i < 2; ++i)
    for (int j = 0; j < 4; ++j)
      for (int r = 0; r < 4; ++r) omax[i][j][r] = -INFINITY;

  for (int f = 0; f < 3; ++f) {
    f32x4 acc[2][8];
    for (int i = 0; i < 2; ++i)
      for (int j = 0; j < 8; ++j) acc[i][j] = (f32x4)0.f;
    for (int kh = 0; kh < 2; ++kh) {
      int gchunk = kh * 4 + l4;
      for (int j = 0; j < 8; ++j) {
        int row = f * 128 + j * 16 + l15;
        int ch = gchunk ^ (row & 7);
        bf16x8 bfr = *(const bf16x8*)&sW[row * 64 + ch * 8];
        for (int i = 0; i < 2; ++i)
          acc[i][j] = __builtin_amdgcn_mfma_f32_16x16x32_bf16(af[i][kh], bfr, acc[i][j], 0, 0, 0);
      }
    }
    for (int j = 0; j < 4; ++j) {
      float bl = bias[(w * 3 + f) * 128 + j * 16 + l15];
      float br = bias[(w * 3 + f) * 128 + 64 + j * 16 + l15];
      for (int i = 0; i < 2; ++i)
        for (int r = 0; r < 4; ++r) {
          float lhs = acc[i][j][r] + bl;
          float rhs = acc[i][j + 4][r] + br;
          float g = lhs / (1.f + __expf(-rhs));
          omax[i][j][r] = fmaxf(omax[i][j][r], g);
        }
    }
  }
  float* Obase = out + ((size_t)bw * N_ + bn * 128 + wid * 32) * C_;
  for (int i = 0; i < 2; ++i)
    for (int j = 0; j < 4; ++j)
      for (int r = 0; r < 4; ++r)
        Obase[(size_t)(i * 16 + l4 * 4 + r) * C_ + j * 16 + l15] = omax[i][j][r];
}

extern "C" void kernel_launch(void* const* d_in, const int* in_sizes, int n_in,
                              void* d_out, int out_size, void* d_ws, size_t ws_size,
                              hipStream_t stream) {
  const float* data = (const float*)d_in[0];
  const float* adj  = (const float*)d_in[1];
  const float* temb = (const float*)d_in[2];
  const float* semb = (const float*)d_in[3];
  const float* W    = (const float*)d_in[4];
  const float* bias = (const float*)d_in[5];
  float* out = (float*)d_out;

  char* ws = (char*)d_ws;
  unsigned short* xbt2  = (unsigned short*)ws;               // 50,331,648 B
  unsigned short* adjb3 = (unsigned short*)(ws + 50331648);  // 25,165,824 B
  unsigned short* wbt   = (unsigned short*)(ws + 75497472);  //    491,520 B
  unsigned short* aggb  = (unsigned short*)(ws + 75988992);  // 41,943,040 B

  hipLaunchKernelGGL(prep_x2,   dim3(12288), dim3(256), 0, stream, data, temb, semb, xbt2);
  hipLaunchKernelGGL(prep_adj3, dim3(6144),  dim3(256), 0, stream, adj, adjb3);
  hipLaunchKernelGGL(prep_w,    dim3(960),   dim3(256), 0, stream, W, wbt);
  hipLaunchKernelGGL(gemm_agg,  dim3(512),   dim3(256), 0, stream, adjb3, xbt2, aggb);
  hipLaunchKernelGGL(glu_out,   dim3(16, 160), dim3(256), 0, stream, aggb, wbt, bias, out);
}

// Round 15
// 322.600 us; speedup vs baseline: 2.6757x; 2.6757x over previous
//
#include <hip/hip_runtime.h>
#include <hip/hip_bf16.h>

#define B_ 16
#define T_ 12
#define N_ 2048
#define C_ 64
#define NW_ 10
#define K_ 6144  // WIN*N

#define NT32 192       // k32 phases

typedef __attribute__((ext_vector_type(8))) short bf16x8;
typedef __attribute__((ext_vector_type(4))) float f32x4;

__device__ __forceinline__ unsigned short f2bf(float f) {
  union { float f; unsigned int u; } v; v.f = f;
  unsigned int u = v.u;
  return (unsigned short)((u + 0x7FFFu + ((u >> 16) & 1u)) >> 16);  // RNE
}

__device__ __forceinline__ void gload16(const void* g, void* l) {
  __builtin_amdgcn_global_load_lds(
      (const __attribute__((address_space(1))) unsigned int*)g,
      (__attribute__((address_space(3))) unsigned int*)l, 16, 0, 0);
}

template<int N>
__device__ __forceinline__ void vmw() {
  if constexpr (N == 5) asm volatile("s_waitcnt vmcnt(5)" ::: "memory");
  else                  asm volatile("s_waitcnt vmcnt(0)" ::: "memory");
}

// ---- prep: x = data + temb + semb -> bf16, blocked layout ----
// xbt2[(b*T+t)*32 + nb][o(8)][c(64)][e(8)] = x[b][t][n=nb*64+o*8+e][c]
__global__ __launch_bounds__(256) void prep_x2(const float* __restrict__ data,
                                               const float* __restrict__ temb,
                                               const float* __restrict__ semb,
                                               unsigned short* __restrict__ xbt2) {
  int idx = blockIdx.x * 256 + threadIdx.x;   // [0, 3145728)
  int q = idx & 511;
  int btnb = idx >> 9;
  int nb = btnb & 31;
  int bt = btnb >> 5;            // b*T + t, < 192
  int t = bt % T_;
  int o = q >> 6, c = q & 63;
  int n0 = nb * 64 + o * 8;
  float te = temb[t * C_ + c];
  union { unsigned short s[8]; uint4 v; } pk;
#pragma unroll
  for (int e = 0; e < 8; ++e) {
    int n = n0 + e;
    float d = data[((size_t)bt * N_ + n) * C_ + c];
    float se = semb[(size_t)n * C_ + c];
    pk.s[e] = f2bf(d + te + se);
  }
  *(uint4*)(xbt2 + (size_t)idx * 8) = pk.v;
}

// ---- prep: adj_mid rows [N..2N) -> bm128-tile granule layout ----
// granule g: s=g&63 (l4=s>>4,l15=s&15); chunk=g>>6: rg=chunk&7, KK=(chunk>>3)&1,
// t=(chunk>>4)%96, bmt=(chunk>>4)/96; elem j = adj_mid[bmt*128+rg*16+l15][t*64+KK*32+l4*8+j]
__global__ __launch_bounds__(256) void prep_adj3(const float* __restrict__ adj,
                                                 unsigned short* __restrict__ adjb3) {
  int idx = blockIdx.x * 256 + threadIdx.x;   // 1,572,864 granules
  int s = idx & 63;
  int l4 = s >> 4, l15 = s & 15;
  int chunk = idx >> 6;
  int rg = chunk & 7;
  int KK = (chunk >> 3) & 1;
  int tb = chunk >> 4;
  int t = tb % 96;
  int bmt = tb / 96;
  int m = bmt * 128 + rg * 16 + l15;
  int k = t * 64 + KK * 32 + l4 * 8;
  const float* src = adj + ((size_t)(N_ + m)) * K_ + k;
  float4 a = *(const float4*)src;
  float4 b4 = *(const float4*)(src + 4);
  union { unsigned short s8[8]; uint4 v; } pk;
  pk.s8[0] = f2bf(a.x);  pk.s8[1] = f2bf(a.y);  pk.s8[2] = f2bf(a.z);  pk.s8[3] = f2bf(a.w);
  pk.s8[4] = f2bf(b4.x); pk.s8[5] = f2bf(b4.y); pk.s8[6] = f2bf(b4.z); pk.s8[7] = f2bf(b4.w);
  *(uint4*)(adjb3 + (size_t)idx * 8) = pk.v;
}

// ---- prep: W -> bf16 transposed [w][f][d][c] ----
__global__ __launch_bounds__(256) void prep_w(const float* __restrict__ W,
                                              unsigned short* __restrict__ wbt) {
  int idx = blockIdx.x * 256 + threadIdx.x;
  int c = idx & 63;
  int d = (idx >> 6) & 127;
  int wf = idx >> 13;
  float v = W[((size_t)wf * 64 + c) * 128 + d];
  wbt[idx] = f2bf(v);
}

// ---- main GEMM: 4-wave blocks, 2/CU (2 barrier domains). A: shared LDS double-buffer
// ---- (16KB only). B: wave-private global->VGPR, prefetched 1 phase ahead (+20 VGPR).
// ---- Per-CU LDS/phase ~80KB (~900cyc) << MFMA 1552cyc -> matrix pipe is the floor.
struct SegCtx {
  const unsigned short* Asrc;    // adjb3 + bmt*786432
  const unsigned short* Xroot;   // xbt2 + (b*T + w0)*C*N
  int lane, wid, wid5, fbase;
  int bconst[5];                 // per-chunk B src offset (incl. lane term)
};

__device__ __forceinline__ void stage_A(const SegCtx& s, unsigned short* ldsA, int u) {
  const unsigned short* As = s.Asrc + (size_t)u * 4096;
  unsigned short* Ad = ldsA + (u & 1) * 4096;
#pragma unroll
  for (int ci = 0; ci < 2; ++ci) {
    int rg = s.wid * 2 + ci;
    gload16(As + rg * 512 + s.lane * 8, Ad + rg * 512);
  }
}

// Phase u: issue A(u+1) stage (2 gloads) + B(u+1) reg loads (5); af ds_reads from
// A(u) [guaranteed by prev phase's vmcnt(5)+barrier]; 40 MFMA on Bc (regs loaded
// last phase, compiler auto-waits); end: vmcnt(5) forces A(u+1) landed -> barrier.
template<int UA>
__device__ __forceinline__ void phase32(const SegCtx& s, unsigned short* ldsA, int u,
                                        bf16x8 (&Bc)[5], bf16x8 (&Bn)[5],
                                        f32x4 (&acc)[8][5]) {
  if (u + 1 < NT32) {
    stage_A(s, ldsA, u + 1);
    __builtin_amdgcn_sched_barrier(0);   // pin: A-gloads before B-loads (vm ledger)
    const unsigned short* Bs = s.Xroot + (size_t)(u + 1) * 2048;
#pragma unroll
    for (int ci = 0; ci < 5; ++ci)
      Bn[ci] = *(const bf16x8*)(Bs + s.bconst[ci]);
    __builtin_amdgcn_sched_barrier(0);
  }
  const unsigned short* Ab = ldsA + UA * 4096;
  bf16x8 af[8];
#pragma unroll
  for (int i = 0; i < 8; ++i)
    af[i] = *(const bf16x8*)(Ab + i * 512 + s.fbase);
  __builtin_amdgcn_s_setprio(1);
#pragma unroll
  for (int i = 0; i < 8; ++i)
#pragma unroll
    for (int c = 0; c < 5; ++c)
      acc[i][c] = __builtin_amdgcn_mfma_f32_16x16x32_bf16(af[i], Bc[c], acc[i][c], 0, 0, 0);
  __builtin_amdgcn_s_setprio(0);
  if (u < NT32 - 1) {
    vmw<5>();                            // newest 5 = B(u+1) regs; forces A(u+1) done
    __builtin_amdgcn_s_barrier();
    __builtin_amdgcn_sched_barrier(0);
  }
}

__global__ __launch_bounds__(256, 2) void gemm_agg(const unsigned short* __restrict__ adjb3,
                                                   const unsigned short* __restrict__ xbt2,
                                                   unsigned short* __restrict__ aggb) {
  __shared__ __align__(16) unsigned short ldsA[2 * 4096];   // 16KB
  int bid = blockIdx.x;
  int bmt = bid & 15;               // bid&7 == bmt&7 -> XCD-resident A (2x1.5MB)
  int bs = bid >> 4;
  int b = bs >> 1;
  int w0 = (bs & 1) * 5;
  int tid = threadIdx.x;
  int lane = tid & 63, wid = tid >> 6;
  int l4 = lane >> 4, l15 = lane & 15;
  SegCtx s;
  s.lane = lane; s.wid = wid;
  s.wid5 = wid * 5;
  s.fbase = l4 * 128 + l15 * 8;
  s.Asrc = adjb3 + (size_t)bmt * 786432;
  s.Xroot = xbt2 + ((size_t)(b * T_ + w0)) * C_ * N_;
  int bOffLane = l4 * 512 + l15 * 8;
#pragma unroll
  for (int ci = 0; ci < 5; ++ci) {
    int cg = s.wid5 + ci;
    s.bconst[ci] = (cg >> 2) * 131072 + (cg & 3) * 128 + bOffLane;
  }

  f32x4 acc[8][5];
#pragma unroll
  for (int i = 0; i < 8; ++i)
#pragma unroll
    for (int c = 0; c < 5; ++c) acc[i][c] = (f32x4)0.f;

  bf16x8 B0[5], B1[5];
  // prologue: A(0) stage + B(0) regs; vmcnt(5) forces A(0) (B(0) auto-waited later)
  __builtin_amdgcn_sched_barrier(0);
  stage_A(s, ldsA, 0);
  __builtin_amdgcn_sched_barrier(0);
#pragma unroll
  for (int ci = 0; ci < 5; ++ci)
    B0[ci] = *(const bf16x8*)(s.Xroot + s.bconst[ci]);
  __builtin_amdgcn_sched_barrier(0);
  vmw<5>();
  __builtin_amdgcn_s_barrier();
  __builtin_amdgcn_sched_barrier(0);

  for (int u = 0; u < NT32; u += 2) {
    phase32<0>(s, ldsA, u,     B0, B1, acc);
    phase32<1>(s, ldsA, u + 1, B1, B0, acc);
  }

  // C-write: bf16 agg [bw][n][c]
  unsigned short* Ob0 = aggb + (size_t)(b * NW_ + w0) * N_ * C_;
#pragma unroll
  for (int c = 0; c < 5; ++c) {
    int col = wid * 80 + c * 16 + l15;
    int g = col >> 6, cc = col & 63;
    unsigned short* Ob = Ob0 + (size_t)g * N_ * C_ + cc;
#pragma unroll
    for (int i = 0; i < 8; ++i) {
      int n0 = bmt * 128 + i * 16 + l4 * 4;
#pragma unroll
      for (int q = 0; q < 4; ++q)
        Ob[(size_t)(n0 + q) * C_] = f2bf(acc[i][c][q]);
    }
  }
}

// ---- epilogue: pre = agg @ W[w,f] + b; glu; max over f ----
__global__ __launch_bounds__(256) void glu_out(const unsigned short* __restrict__ aggb,
                                               const unsigned short* __restrict__ wbt,
                                               const float* __restrict__ bias,
                                               float* __restrict__ out) {
  __shared__ __align__(16) unsigned short sW[3 * 128 * 64];
  int bn = blockIdx.x, bw = blockIdx.y;
  int w = bw % NW_;
  int tid = threadIdx.x, lane = tid & 63, wid = tid >> 6;
  int lrow8 = lane >> 3, jl = lane & 7;
  int l15 = lane & 15, l4 = lane >> 4;
  const unsigned short* Wsrc = wbt + (size_t)w * 3 * 128 * 64;
  for (int ci = 0; ci < 12; ++ci) {
    int chunk = wid * 12 + ci;
    int row = chunk * 8 + lrow8;
    int jg = jl ^ (row & 7);
    gload16(Wsrc + (size_t)row * 64 + jg * 8, &sW[chunk * 512]);
  }
  const unsigned short* Abase = aggb + ((size_t)bw * N_ + bn * 128 + wid * 32) * C_;
  bf16x8 af[2][2];
  for (int i = 0; i < 2; ++i)
    for (int kh = 0; kh < 2; ++kh)
      af[i][kh] = *(const bf16x8*)(Abase + (size_t)(i * 16 + l15) * C_ + kh * 32 + l4 * 8);
  __syncthreads();

  float omax[2][4][4];
  for (int i = 0; i < 2; ++i)
    for (int j = 0; j < 4; ++j)
      for (int r = 0; r < 4; ++r) omax[i][j][r] = -INFINITY;

  for (int f = 0; f < 3; ++f) {
    f32x4 acc[2][8];
    for (int i = 0; i < 2; ++i)
      for (int j = 0; j < 8; ++j) acc[i][j] = (f32x4)0.f;
    for (int kh = 0; kh < 2; ++kh) {
      int gchunk = kh * 4 + l4;
      for (int j = 0; j < 8; ++j) {
        int row = f * 128 + j * 16 + l15;
        int ch = gchunk ^ (row & 7);
        bf16x8 bfr = *(const bf16x8*)&sW[row * 64 + ch * 8];
        for (int i = 0; i < 2; ++i)
          acc[i][j] = __builtin_amdgcn_mfma_f32_16x16x32_bf16(af[i][kh], bfr, acc[i][j], 0, 0, 0);
      }
    }
    for (int j = 0; j < 4; ++j) {
      float bl = bias[(w * 3 + f) * 128 + j * 16 + l15];
      float br = bias[(w * 3 + f) * 128 + 64 + j * 16 + l15];
      for (int i = 0; i < 2; ++i)
        for (int r = 0; r < 4; ++r) {
          float lhs = acc[i][j][r] + bl;
          float rhs = acc[i][j + 4][r] + br;
          float g = lhs / (1.f + __expf(-rhs));
          omax[i][j][r] = fmaxf(omax[i][j][r], g);
        }
    }
  }
  float* Obase = out + ((size_t)bw * N_ + bn * 128 + wid * 32) * C_;
  for (int i = 0; i < 2; ++i)
    for (int j = 0; j < 4; ++j)
      for (int r = 0; r < 4; ++r)
        Obase[(size_t)(i * 16 + l4 * 4 + r) * C_ + j * 16 + l15] = omax[i][j][r];
}

extern "C" void kernel_launch(void* const* d_in, const int* in_sizes, int n_in,
                              void* d_out, int out_size, void* d_ws, size_t ws_size,
                              hipStream_t stream) {
  const float* data = (const float*)d_in[0];
  const float* adj  = (const float*)d_in[1];
  const float* temb = (const float*)d_in[2];
  const float* semb = (const float*)d_in[3];
  const float* W    = (const float*)d_in[4];
  const float* bias = (const float*)d_in[5];
  float* out = (float*)d_out;

  char* ws = (char*)d_ws;
  unsigned short* xbt2  = (unsigned short*)ws;               // 50,331,648 B
  unsigned short* adjb3 = (unsigned short*)(ws + 50331648);  // 25,165,824 B
  unsigned short* wbt   = (unsigned short*)(ws + 75497472);  //    491,520 B
  unsigned short* aggb  = (unsigned short*)(ws + 75988992);  // 41,943,040 B

  hipLaunchKernelGGL(prep_x2,   dim3(12288), dim3(256), 0, stream, data, temb, semb, xbt2);
  hipLaunchKernelGGL(prep_adj3, dim3(6144),  dim3(256), 0, stream, adj, adjb3);
  hipLaunchKernelGGL(prep_w,    dim3(960),   dim3(256), 0, stream, W, wbt);
  hipLaunchKernelGGL(gemm_agg,  dim3(512),   dim3(256), 0, stream, adjb3, xbt2, aggb);
  hipLaunchKernelGGL(glu_out,   dim3(16, 160), dim3(256), 0, stream, aggb, wbt, bias, out);
}

// Round 16
// 313.838 us; speedup vs baseline: 2.7504x; 1.0279x over previous
//
#include <hip/hip_runtime.h>
#include <hip/hip_bf16.h>

#define B_ 16
#define T_ 12
#define N_ 2048
#define C_ 64
#define NW_ 10
#define K_ 6144  // WIN*N

#define NT32 192       // k32 phases
#define ALDS32 4096    // A elems per k32 LDS buffer (128 rows x 32 k)
#define BLDS32 10240   // B elems per k32 LDS buffer (320 cols x 32 k)

typedef __attribute__((ext_vector_type(8))) short bf16x8;
typedef __attribute__((ext_vector_type(4))) float f32x4;

__device__ __forceinline__ unsigned short f2bf(float f) {
  union { float f; unsigned int u; } v; v.f = f;
  unsigned int u = v.u;
  return (unsigned short)((u + 0x7FFFu + ((u >> 16) & 1u)) >> 16);  // RNE
}

__device__ __forceinline__ void gload16(const void* g, void* l) {
  __builtin_amdgcn_global_load_lds(
      (const __attribute__((address_space(1))) unsigned int*)g,
      (__attribute__((address_space(3))) unsigned int*)l, 16, 0, 0);
}

template<int N>
__device__ __forceinline__ void vmw() {
  if constexpr (N == 5) asm volatile("s_waitcnt vmcnt(5)" ::: "memory");
  else                  asm volatile("s_waitcnt vmcnt(0)" ::: "memory");
}

// ---- prep: x = data + temb + semb -> bf16, blocked layout ----
// xbt2[(b*T+t)*32 + nb][o(8)][c(64)][e(8)] = x[b][t][n=nb*64+o*8+e][c]
__global__ __launch_bounds__(256) void prep_x2(const float* __restrict__ data,
                                               const float* __restrict__ temb,
                                               const float* __restrict__ semb,
                                               unsigned short* __restrict__ xbt2) {
  int idx = blockIdx.x * 256 + threadIdx.x;   // [0, 3145728)
  int q = idx & 511;
  int btnb = idx >> 9;
  int nb = btnb & 31;
  int bt = btnb >> 5;            // b*T + t, < 192
  int t = bt % T_;
  int o = q >> 6, c = q & 63;
  int n0 = nb * 64 + o * 8;
  float te = temb[t * C_ + c];
  union { unsigned short s[8]; uint4 v; } pk;
#pragma unroll
  for (int e = 0; e < 8; ++e) {
    int n = n0 + e;
    float d = data[((size_t)bt * N_ + n) * C_ + c];
    float se = semb[(size_t)n * C_ + c];
    pk.s[e] = f2bf(d + te + se);
  }
  *(uint4*)(xbt2 + (size_t)idx * 8) = pk.v;
}

// ---- prep: adj_mid rows [N..2N) -> bm128-tile granule layout ----
// granule g: s=g&63 (l4=s>>4,l15=s&15); chunk=g>>6: rg=chunk&7, KK=(chunk>>3)&1,
// t=(chunk>>4)%96, bmt=(chunk>>4)/96; elem j = adj_mid[bmt*128+rg*16+l15][t*64+KK*32+l4*8+j]
__global__ __launch_bounds__(256) void prep_adj3(const float* __restrict__ adj,
                                                 unsigned short* __restrict__ adjb3) {
  int idx = blockIdx.x * 256 + threadIdx.x;   // 1,572,864 granules
  int s = idx & 63;
  int l4 = s >> 4, l15 = s & 15;
  int chunk = idx >> 6;
  int rg = chunk & 7;
  int KK = (chunk >> 3) & 1;
  int tb = chunk >> 4;
  int t = tb % 96;
  int bmt = tb / 96;
  int m = bmt * 128 + rg * 16 + l15;
  int k = t * 64 + KK * 32 + l4 * 8;
  const float* src = adj + ((size_t)(N_ + m)) * K_ + k;
  float4 a = *(const float4*)src;
  float4 b4 = *(const float4*)(src + 4);
  union { unsigned short s8[8]; uint4 v; } pk;
  pk.s8[0] = f2bf(a.x);  pk.s8[1] = f2bf(a.y);  pk.s8[2] = f2bf(a.z);  pk.s8[3] = f2bf(a.w);
  pk.s8[4] = f2bf(b4.x); pk.s8[5] = f2bf(b4.y); pk.s8[6] = f2bf(b4.z); pk.s8[7] = f2bf(b4.w);
  *(uint4*)(adjb3 + (size_t)idx * 8) = pk.v;
}

// ---- prep: W -> bf16 transposed [w][f][d][c] ----
__global__ __launch_bounds__(256) void prep_w(const float* __restrict__ W,
                                              unsigned short* __restrict__ wbt) {
  int idx = blockIdx.x * 256 + threadIdx.x;
  int c = idx & 63;
  int d = (idx >> 6) & 127;
  int wf = idx >> 13;
  float v = W[((size_t)wf * 64 + c) * 128 + d];
  wbt[idx] = f2bf(v);
}

// ---- main GEMM: r13 structure (4-wave blocks, 2/CU, A k32-dbuf + B k32-3buf,
// ---- vmcnt(5) ledger, 1 barrier/phase) + anti-phase stagger seed for co-resident
// ---- block pairs (bid, bid+256).
struct SegCtx {
  const unsigned short* Asrc;    // adjb3 + bmt*786432
  const unsigned short* Xroot;   // xbt2 + (b*T + w0)*C*N
  int lane, wid, wid5, l4, l15, fbase;
  int bconst[5];                 // per-chunk B src offset (incl. lane term)
};

template<int UA, int UB3>
__device__ __forceinline__ void phase32(const SegCtx& s, unsigned short* ldsA,
                                        unsigned short* ldsB, int u, f32x4 (&acc)[8][5]) {
  if (u + 1 < NT32) {            // stage A(u+1): 2 gloads
    const unsigned short* As = s.Asrc + (size_t)(u + 1) * 4096;
    unsigned short* Ad = ldsA + (UA ^ 1) * ALDS32;
#pragma unroll
    for (int ci = 0; ci < 2; ++ci) {
      int rg = s.wid * 2 + ci;
      gload16(As + rg * 512 + s.lane * 8, Ad + rg * 512);
    }
  }
  if (u + 2 < NT32) {            // stage B(u+2): 5 gloads
    const unsigned short* Bs = s.Xroot + (size_t)(u + 2) * 2048;
    unsigned short* Bd = ldsB + ((UB3 + 2) % 3) * BLDS32;
#pragma unroll
    for (int ci = 0; ci < 5; ++ci) {
      int cg = s.wid5 + ci;
      gload16(Bs + s.bconst[ci], Bd + cg * 512);
    }
  }
  const unsigned short* Ab = ldsA + UA * ALDS32;
  const unsigned short* Bb = ldsB + UB3 * BLDS32;
  bf16x8 af[8], bfv[5];
#pragma unroll
  for (int c = 0; c < 5; ++c)
    bfv[c] = *(const bf16x8*)(Bb + (s.wid5 + c) * 512 + s.fbase);
#pragma unroll
  for (int i = 0; i < 8; ++i)
    af[i] = *(const bf16x8*)(Ab + i * 512 + s.fbase);
  __builtin_amdgcn_s_setprio(1);
#pragma unroll
  for (int i = 0; i < 8; ++i)
#pragma unroll
    for (int c = 0; c < 5; ++c)
      acc[i][c] = __builtin_amdgcn_mfma_f32_16x16x32_bf16(af[i], bfv[c], acc[i][c], 0, 0, 0);
  __builtin_amdgcn_s_setprio(0);
  if (u < NT32 - 2) vmw<5>();
  else if (u == NT32 - 2) vmw<0>();
  if (u < NT32 - 1) {
    __builtin_amdgcn_s_barrier();
    __builtin_amdgcn_sched_barrier(0);
  }
}

__global__ __launch_bounds__(256, 2) void gemm_agg(const unsigned short* __restrict__ adjb3,
                                                   const unsigned short* __restrict__ xbt2,
                                                   unsigned short* __restrict__ aggb) {
  __shared__ __align__(16) unsigned short ldsA[2 * ALDS32];   // 16KB
  __shared__ __align__(16) unsigned short ldsB[3 * BLDS32];   // 60KB
  int bid = blockIdx.x;
  int bmt = bid & 15;               // bid&7 == bmt&7 -> XCD-resident A (2x1.5MB)
  int bs = bid >> 4;
  int b = bs >> 1;
  int w0 = (bs & 1) * 5;
  int tid = threadIdx.x;
  SegCtx s;
  s.lane = tid & 63; s.wid = tid >> 6;
  s.wid5 = s.wid * 5;
  s.l4 = s.lane >> 4; s.l15 = s.lane & 15;
  s.fbase = s.l4 * 128 + s.l15 * 8;
  s.Asrc = adjb3 + (size_t)bmt * 786432;
  s.Xroot = xbt2 + ((size_t)(b * T_ + w0)) * C_ * N_;
  int bOffLane = s.l4 * 512 + s.l15 * 8;
#pragma unroll
  for (int ci = 0; ci < 5; ++ci) {
    int cg = s.wid5 + ci;
    s.bconst[ci] = (cg >> 2) * 131072 + (cg & 3) * 128 + bOffLane;
  }

  // Anti-phase seed: breadth-first dispatch puts bid and bid+256 on the same CU;
  // delay the second arrival by ~half a phase (~1280 cyc) so the two barrier
  // domains interleave LDS-burst and MFMA-burst instead of colliding.
  if ((bid >> 8) & 1) {
#pragma unroll
    for (int i = 0; i < 20; ++i)
      asm volatile("s_sleep 1" ::: "memory");
  }

  f32x4 acc[8][5];
#pragma unroll
  for (int i = 0; i < 8; ++i)
#pragma unroll
    for (int c = 0; c < 5; ++c) acc[i][c] = (f32x4)0.f;

  // prologue: A(0)->bufA0 (2), B(0)->bufB0 (5), B(1)->bufB1 (5); vmcnt(5): A0+B0 done
  __builtin_amdgcn_sched_barrier(0);
#pragma unroll
  for (int ci = 0; ci < 2; ++ci) {
    int rg = s.wid * 2 + ci;
    gload16(s.Asrc + rg * 512 + s.lane * 8, ldsA + rg * 512);
  }
#pragma unroll
  for (int ci = 0; ci < 5; ++ci)
    gload16(s.Xroot + s.bconst[ci], ldsB + (s.wid5 + ci) * 512);
#pragma unroll
  for (int ci = 0; ci < 5; ++ci)
    gload16(s.Xroot + 2048 + s.bconst[ci], ldsB + BLDS32 + (s.wid5 + ci) * 512);
  vmw<5>();
  __builtin_amdgcn_s_barrier();
  __builtin_amdgcn_sched_barrier(0);

  for (int it = 0; it < NT32 / 6; ++it) {
    int u = it * 6;
    phase32<0, 0>(s, ldsA, ldsB, u,     acc);
    phase32<1, 1>(s, ldsA, ldsB, u + 1, acc);
    phase32<0, 2>(s, ldsA, ldsB, u + 2, acc);
    phase32<1, 0>(s, ldsA, ldsB, u + 3, acc);
    phase32<0, 1>(s, ldsA, ldsB, u + 4, acc);
    phase32<1, 2>(s, ldsA, ldsB, u + 5, acc);
  }

  // C-write: bf16 agg [bw][n][c]
  unsigned short* Ob0 = aggb + (size_t)(b * NW_ + w0) * N_ * C_;
#pragma unroll
  for (int c = 0; c < 5; ++c) {
    int col = s.wid * 80 + c * 16 + s.l15;
    int g = col >> 6, cc = col & 63;
    unsigned short* Ob = Ob0 + (size_t)g * N_ * C_ + cc;
#pragma unroll
    for (int i = 0; i < 8; ++i) {
      int n0 = bmt * 128 + i * 16 + s.l4 * 4;
#pragma unroll
      for (int q = 0; q < 4; ++q)
        Ob[(size_t)(n0 + q) * C_] = f2bf(acc[i][c][q]);
    }
  }
}

// ---- epilogue: pre = agg @ W[w,f] + b; glu; max over f ----
__global__ __launch_bounds__(256) void glu_out(const unsigned short* __restrict__ aggb,
                                               const unsigned short* __restrict__ wbt,
                                               const float* __restrict__ bias,
                                               float* __restrict__ out) {
  __shared__ __align__(16) unsigned short sW[3 * 128 * 64];
  int bn = blockIdx.x, bw = blockIdx.y;
  int w = bw % NW_;
  int tid = threadIdx.x, lane = tid & 63, wid = tid >> 6;
  int lrow8 = lane >> 3, jl = lane & 7;
  int l15 = lane & 15, l4 = lane >> 4;
  const unsigned short* Wsrc = wbt + (size_t)w * 3 * 128 * 64;
  for (int ci = 0; ci < 12; ++ci) {
    int chunk = wid * 12 + ci;
    int row = chunk * 8 + lrow8;
    int jg = jl ^ (row & 7);
    gload16(Wsrc + (size_t)row * 64 + jg * 8, &sW[chunk * 512]);
  }
  const unsigned short* Abase = aggb + ((size_t)bw * N_ + bn * 128 + wid * 32) * C_;
  bf16x8 af[2][2];
  for (int i = 0; i < 2; ++i)
    for (int kh = 0; kh < 2; ++kh)
      af[i][kh] = *(const bf16x8*)(Abase + (size_t)(i * 16 + l15) * C_ + kh * 32 + l4 * 8);
  __syncthreads();

  float omax[2][4][4];
  for (int i = 0; i < 2; ++i)
    for (int j = 0; j < 4; ++j)
      for (int r = 0; r < 4; ++r) omax[i][j][r] = -INFINITY;

  for (int f = 0; f < 3; ++f) {
    f32x4 acc[2][8];
    for (int i = 0; i < 2; ++i)
      for (int j = 0; j < 8; ++j) acc[i][j] = (f32x4)0.f;
    for (int kh = 0; kh < 2; ++kh) {
      int gchunk = kh * 4 + l4;
      for (int j = 0; j < 8; ++j) {
        int row = f * 128 + j * 16 + l15;
        int ch = gchunk ^ (row & 7);
        bf16x8 bfr = *(const bf16x8*)&sW[row * 64 + ch * 8];
        for (int i = 0; i < 2; ++i)
          acc[i][j] = __builtin_amdgcn_mfma_f32_16x16x32_bf16(af[i][kh], bfr, acc[i][j], 0, 0, 0);
      }
    }
    for (int j = 0; j < 4; ++j) {
      float bl = bias[(w * 3 + f) * 128 + j * 16 + l15];
      float br = bias[(w * 3 + f) * 128 + 64 + j * 16 + l15];
      for (int i = 0; i < 2; ++i)
        for (int r = 0; r < 4; ++r) {
          float lhs = acc[i][j][r] + bl;
          float rhs = acc[i][j + 4][r] + br;
          float g = lhs / (1.f + __expf(-rhs));
          omax[i][j][r] = fmaxf(omax[i][j][r], g);
        }
    }
  }
  float* Obase = out + ((size_t)bw * N_ + bn * 128 + wid * 32) * C_;
  for (int i = 0; i < 2; ++i)
    for (int j = 0; j < 4; ++j)
      for (int r = 0; r < 4; ++r)
        Obase[(size_t)(i * 16 + l4 * 4 + r) * C_ + j * 16 + l15] = omax[i][j][r];
}

extern "C" void kernel_launch(void* const* d_in, const int* in_sizes, int n_in,
                              void* d_out, int out_size, void* d_ws, size_t ws_size,
                              hipStream_t stream) {
  const float* data = (const float*)d_in[0];
  const float* adj  = (const float*)d_in[1];
  const float* temb = (const float*)d_in[2];
  const float* semb = (const float*)d_in[3];
  const float* W    = (const float*)d_in[4];
  const float* bias = (const float*)d_in[5];
  float* out = (float*)d_out;

  char* ws = (char*)d_ws;
  unsigned short* xbt2  = (unsigned short*)ws;               // 50,331,648 B
  unsigned short* adjb3 = (unsigned short*)(ws + 50331648);  // 25,165,824 B
  unsigned short* wbt   = (unsigned short*)(ws + 75497472);  //    491,520 B
  unsigned short* aggb  = (unsigned short*)(ws + 75988992);  // 41,943,040 B

  hipLaunchKernelGGL(prep_x2,   dim3(12288), dim3(256), 0, stream, data, temb, semb, xbt2);
  hipLaunchKernelGGL(prep_adj3, dim3(6144),  dim3(256), 0, stream, adj, adjb3);
  hipLaunchKernelGGL(prep_w,    dim3(960),   dim3(256), 0, stream, W, wbt);
  hipLaunchKernelGGL(gemm_agg,  dim3(512),   dim3(256), 0, stream, adjb3, xbt2, aggb);
  hipLaunchKernelGGL(glu_out,   dim3(16, 160), dim3(256), 0, stream, aggb, wbt, bias, out);
}